// Round 3
// baseline (135.042 us; speedup 1.0000x reference)
//
#include <hip/hip_runtime.h>

// Batched 4096-point forward FFT (real input), 2048 rows.
// Two real rows per block via one complex FFT + Hermitian split.
// 4096 = 16*16*16: three radix-16 register stages, two LDS transposes,
// plus one LDS round-trip for the Z[k] <-> Z[N-k] pairing.
// out[0 : B*N] = Re(FFT), out[B*N : 2*B*N] = Im(FFT), natural order.

constexpr int NFFT  = 4096;
constexpr int BATCH = 2048;
constexpr int RS    = 18;     // float2 elements per 16-wide LDS row (+2 pad)

struct cplx { float re, im; };
__device__ __forceinline__ cplx cmul(cplx a, cplx b){ return {a.re*b.re - a.im*b.im, a.re*b.im + a.im*b.re}; }
__device__ __forceinline__ cplx cadd(cplx a, cplx b){ return {a.re+b.re, a.im+b.im}; }
__device__ __forceinline__ cplx csub(cplx a, cplx b){ return {a.re-b.re, a.im-b.im}; }
__device__ __forceinline__ cplx cnegi(cplx a){ return { a.im, -a.re }; }   // a * (-i)

// forward radix-4: X[k] = sum_n z[n] (-i)^(nk), in-place over the 4 refs
__device__ __forceinline__ void dft4(cplx& a, cplx& b, cplx& c, cplx& d){
    cplx t0 = cadd(a,c), t1 = csub(a,c), t2 = cadd(b,d);
    cplx t3n = cnegi(csub(b,d));          // -i*(b-d)
    a = cadd(t0,t2);
    cplx nb = cadd(t1,t3n);
    c = csub(t0,t2);
    d = csub(t1,t3n);
    b = nb;
}

// RIDX[r] = 4*(r&3) + (r>>2): after dft16, output Y[r] sits in z[RIDX[r]]
__device__ __forceinline__ constexpr int RIDX(int r){ return 4*(r&3) + (r>>2); }

// in-place forward DFT-16 (digit-reversed output placement per RIDX)
__device__ __forceinline__ void dft16(cplx z[16]){
    dft4(z[0], z[4], z[8],  z[12]);
    dft4(z[1], z[5], z[9],  z[13]);
    dft4(z[2], z[6], z[10], z[14]);
    dft4(z[3], z[7], z[11], z[15]);
    constexpr float C1 = 0.92387953251128675613f;   // cos(pi/8)
    constexpr float S1 = 0.38268343236508977173f;   // sin(pi/8)
    constexpr float R2 = 0.70710678118654752440f;   // sqrt(2)/2
    z[5]  = cmul(z[5],  { C1,-S1});   // w16^1
    z[6]  = cmul(z[6],  { R2,-R2});   // w16^2
    z[7]  = cmul(z[7],  { S1,-C1});   // w16^3
    z[9]  = cmul(z[9],  { R2,-R2});   // w16^2
    z[10] = cnegi(z[10]);             // w16^4 = -i
    z[11] = cmul(z[11], {-R2,-R2});   // w16^6
    z[13] = cmul(z[13], { S1,-C1});   // w16^3
    z[14] = cmul(z[14], {-R2,-R2});   // w16^6
    z[15] = cmul(z[15], {-C1, S1});   // w16^9
    dft4(z[0],  z[1],  z[2],  z[3]);
    dft4(z[4],  z[5],  z[6],  z[7]);
    dft4(z[8],  z[9],  z[10], z[11]);
    dft4(z[12], z[13], z[14], z[15]);
}

// multiply output r (at z[RIDX(r)]) by w^r, w = e^{-2*pi*i*rev}
__device__ __forceinline__ void twiddle_all(cplx z[16], float rev){
    float ang = rev * 6.28318530717958647692f;
    float s = __sinf(ang), c = __cosf(ang);
    cplx w[16];
    w[0] = {1.0f, 0.0f};
    w[1] = {c, -s};
#pragma unroll
    for (int r = 2; r < 16; ++r) w[r] = cmul(w[r>>1], w[(r+1)>>1]);
#pragma unroll
    for (int r = 1; r < 16; ++r) z[RIDX(r)] = cmul(z[RIDX(r)], w[r]);
}

__global__ __launch_bounds__(256, 4)
void fft4096_r16x2(const float* __restrict__ x, float* __restrict__ out) {
    __shared__ float2 su[256 * RS];          // 36864 B (>= 4096 float2)

    const int pair = blockIdx.x;             // handles rows 2*pair, 2*pair+1
    const int t    = threadIdx.x;            // 0..255
    const float* __restrict__ xa = x + (size_t)(2*pair) * NFFT;
    const float* __restrict__ xb = xa + NFFT;

    cplx z[16];

    // ---- stage A: z = xa + i*xb packed; thread t = n2, DFT16 over n1,
    //      twiddle w4096^(r*n2).
#pragma unroll
    for (int n1 = 0; n1 < 16; ++n1) z[n1] = { xa[n1*256 + t], xb[n1*256 + t] };
    dft16(z);
    twiddle_all(z, (float)t * (1.0f/4096.0f));
#pragma unroll
    for (int r = 0; r < 16; ++r) su[t*RS + r] = { z[RIDX(r)].re, z[RIDX(r)].im };

    __syncthreads();

    // ---- stage B: thread (k1 = t>>4, m2 = t&15), DFT16 over m1,
    //      twiddle w256^(k2*m2).
    {
        const int k1 = t >> 4, m2 = t & 15;
#pragma unroll
        for (int m1 = 0; m1 < 16; ++m1) {
            float2 v = su[(16*m1 + m2)*RS + k1];
            z[m1] = { v.x, v.y };
        }
        dft16(z);
        twiddle_all(z, (float)m2 * (1.0f/256.0f));
        __syncthreads();
#pragma unroll
        for (int k2 = 0; k2 < 16; ++k2)
            su[(k1*16 + k2)*RS + m2] = { z[RIDX(k2)].re, z[RIDX(k2)].im };
    }

    __syncthreads();

    // ---- stage C: thread (k1 = t&15, k2 = t>>4), DFT16 over m2 (no twiddle).
    //      Result: Z[t + 256*k3] = z[RIDX(k3)].
    {
        const int k1 = t & 15, k2 = t >> 4;
#pragma unroll
        for (int m2 = 0; m2 < 16; ++m2) {
            float2 v = su[(k1*16 + k2)*RS + m2];
            z[m2] = { v.x, v.y };
        }
        dft16(z);
    }

    __syncthreads();   // all su reads done before overwrite

    // ---- deposit Z[k] flat for the Hermitian pairing
#pragma unroll
    for (int r = 0; r < 16; ++r)
        su[t + 256*r] = { z[RIDX(r)].re, z[RIDX(r)].im };

    __syncthreads();

    // ---- Hermitian split and store:
    //      Xa[k] = (Z[k]+conj(Z[-k]))/2,  Xb[k] = (Z[k]-conj(Z[-k]))/(2i)
    float* __restrict__ outAre = out + (size_t)(2*pair) * NFFT;
    float* __restrict__ outAim = out + (size_t)BATCH * NFFT + (size_t)(2*pair) * NFFT;
    float* __restrict__ outBre = outAre + NFFT;
    float* __restrict__ outBim = outAim + NFFT;
#pragma unroll
    for (int r = 0; r < 16; ++r) {
        const int k = t + 256*r;
        float2 Zk = su[k];
        float2 Zm = su[(NFFT - k) & (NFFT - 1)];
        outAre[k] = 0.5f * (Zk.x + Zm.x);
        outAim[k] = 0.5f * (Zk.y - Zm.y);
        outBre[k] = 0.5f * (Zk.y + Zm.y);
        outBim[k] = 0.5f * (Zm.x - Zk.x);
    }
}

extern "C" void kernel_launch(void* const* d_in, const int* in_sizes, int n_in,
                              void* d_out, int out_size, void* d_ws, size_t ws_size,
                              hipStream_t stream) {
    (void)in_sizes; (void)n_in; (void)d_ws; (void)ws_size; (void)out_size;
    const float* x = (const float*)d_in[0];   // (2048, 4096) fp32
    float* out = (float*)d_out;               // re plane then im plane
    fft4096_r16x2<<<dim3(BATCH / 2), dim3(256), 0, stream>>>(x, out);
}

// Round 4
// 132.225 us; speedup vs baseline: 1.0213x; 1.0213x over previous
//
#include <hip/hip_runtime.h>

// Batched 4096-point forward FFT (real input), 2048 rows.
// 4096 = 16 * 16 * 16: three radix-16 register stages, two LDS transposes.
// out[0 : B*N] = Re(FFT), out[B*N : 2*B*N] = Im(FFT), natural order.
//
// R3 post-mortem: Hermitian two-rows-per-block variant regressed 133->135 us
// (extra LDS round-trip + 2 barriers outweighed halved FFT math -> kernel is
// memory-bound, not compute-bound). Reverted to this (best-measured) form.

constexpr int NFFT  = 4096;
constexpr int BATCH = 2048;
constexpr int RS    = 18;     // float2 elements per 16-wide LDS row (+2 pad)

struct cplx { float re, im; };
__device__ __forceinline__ cplx cmul(cplx a, cplx b){ return {a.re*b.re - a.im*b.im, a.re*b.im + a.im*b.re}; }
__device__ __forceinline__ cplx cadd(cplx a, cplx b){ return {a.re+b.re, a.im+b.im}; }
__device__ __forceinline__ cplx csub(cplx a, cplx b){ return {a.re-b.re, a.im-b.im}; }
__device__ __forceinline__ cplx cnegi(cplx a){ return { a.im, -a.re }; }   // a * (-i)

// forward radix-4: X[k] = sum_n z[n] (-i)^(nk), in-place over the 4 refs
__device__ __forceinline__ void dft4(cplx& a, cplx& b, cplx& c, cplx& d){
    cplx t0 = cadd(a,c), t1 = csub(a,c), t2 = cadd(b,d);
    cplx t3n = cnegi(csub(b,d));          // -i*(b-d)
    a = cadd(t0,t2);
    cplx nb = cadd(t1,t3n);
    c = csub(t0,t2);
    d = csub(t1,t3n);
    b = nb;
}

// RIDX[r] = 4*(r&3) + (r>>2): after dft16, output Y[r] sits in z[RIDX[r]]
__device__ __forceinline__ constexpr int RIDX(int r){ return 4*(r&3) + (r>>2); }

// in-place forward DFT-16 (digit-reversed output placement per RIDX)
__device__ __forceinline__ void dft16(cplx z[16]){
    dft4(z[0], z[4], z[8],  z[12]);
    dft4(z[1], z[5], z[9],  z[13]);
    dft4(z[2], z[6], z[10], z[14]);
    dft4(z[3], z[7], z[11], z[15]);
    constexpr float C1 = 0.92387953251128675613f;   // cos(pi/8)
    constexpr float S1 = 0.38268343236508977173f;   // sin(pi/8)
    constexpr float R2 = 0.70710678118654752440f;   // sqrt(2)/2
    z[5]  = cmul(z[5],  { C1,-S1});   // w16^1
    z[6]  = cmul(z[6],  { R2,-R2});   // w16^2
    z[7]  = cmul(z[7],  { S1,-C1});   // w16^3
    z[9]  = cmul(z[9],  { R2,-R2});   // w16^2
    z[10] = cnegi(z[10]);             // w16^4 = -i
    z[11] = cmul(z[11], {-R2,-R2});   // w16^6
    z[13] = cmul(z[13], { S1,-C1});   // w16^3
    z[14] = cmul(z[14], {-R2,-R2});   // w16^6
    z[15] = cmul(z[15], {-C1, S1});   // w16^9
    dft4(z[0],  z[1],  z[2],  z[3]);
    dft4(z[4],  z[5],  z[6],  z[7]);
    dft4(z[8],  z[9],  z[10], z[11]);
    dft4(z[12], z[13], z[14], z[15]);
}

// multiply output r (at z[RIDX(r)]) by w^r, w = e^{-2*pi*i*rev},
// using native v_sin/v_cos + logarithmic powering.
__device__ __forceinline__ void twiddle_all(cplx z[16], float rev){
    float ang = rev * 6.28318530717958647692f;
    float s = __sinf(ang), c = __cosf(ang);
    cplx w[16];
    w[0] = {1.0f, 0.0f};
    w[1] = {c, -s};
#pragma unroll
    for (int r = 2; r < 16; ++r) w[r] = cmul(w[r>>1], w[(r+1)>>1]);
#pragma unroll
    for (int r = 1; r < 16; ++r) z[RIDX(r)] = cmul(z[RIDX(r)], w[r]);
}

__global__ __launch_bounds__(256, 4)
void fft4096_r16(const float* __restrict__ x, float* __restrict__ out) {
    __shared__ float2 su[256 * RS];          // 36864 B

    const int row = blockIdx.x;
    const int t   = threadIdx.x;             // 0..255
    const float* __restrict__ xr = x + (size_t)row * NFFT;

    cplx z[16];

    // ---- stage A: thread t = n2. z[n1] = x[256*n1 + n2], DFT16 over n1,
    //      twiddle w4096^(r*n2).
#pragma unroll
    for (int n1 = 0; n1 < 16; ++n1) z[n1] = { xr[n1*256 + t], 0.0f };
    dft16(z);
    twiddle_all(z, (float)t * (1.0f/4096.0f));
#pragma unroll
    for (int r = 0; r < 16; ++r) su[t*RS + r] = { z[RIDX(r)].re, z[RIDX(r)].im };

    __syncthreads();

    // ---- stage B: thread (k1 = t>>4, m2 = t&15). z[m1] = u[k1][16*m1+m2],
    //      DFT16 over m1, twiddle w256^(k2*m2).
    {
        const int k1 = t >> 4, m2 = t & 15;
#pragma unroll
        for (int m1 = 0; m1 < 16; ++m1) {
            float2 v = su[(16*m1 + m2)*RS + k1];
            z[m1] = { v.x, v.y };
        }
        dft16(z);
        twiddle_all(z, (float)m2 * (1.0f/256.0f));
        __syncthreads();   // all reads of su done before overwrite
#pragma unroll
        for (int k2 = 0; k2 < 16; ++k2)
            su[(k1*16 + k2)*RS + m2] = { z[RIDX(k2)].re, z[RIDX(k2)].im };
    }

    __syncthreads();

    // ---- stage C: thread (k1 = t&15, k2 = t>>4). z[m2] = v[k1][k2][m2],
    //      DFT16 over m2 (no twiddle). X[t + 256*k3].
    {
        const int k1 = t & 15, k2 = t >> 4;
#pragma unroll
        for (int m2 = 0; m2 < 16; ++m2) {
            float2 v = su[(k1*16 + k2)*RS + m2];
            z[m2] = { v.x, v.y };
        }
        dft16(z);
        float* __restrict__ outRe = out + (size_t)row * NFFT;
        float* __restrict__ outIm = out + (size_t)BATCH * NFFT + (size_t)row * NFFT;
#pragma unroll
        for (int k3 = 0; k3 < 16; ++k3) {
            outRe[t + 256*k3] = z[RIDX(k3)].re;
            outIm[t + 256*k3] = z[RIDX(k3)].im;
        }
    }
}

extern "C" void kernel_launch(void* const* d_in, const int* in_sizes, int n_in,
                              void* d_out, int out_size, void* d_ws, size_t ws_size,
                              hipStream_t stream) {
    (void)in_sizes; (void)n_in; (void)d_ws; (void)ws_size; (void)out_size;
    const float* x = (const float*)d_in[0];   // (2048, 4096) fp32
    float* out = (float*)d_out;               // re plane then im plane
    fft4096_r16<<<dim3(BATCH), dim3(256), 0, stream>>>(x, out);
}